// Round 5
// baseline (12766.841 us; speedup 1.0000x reference)
//
#include <hip/hip_runtime.h>

#define BB 1024
#define TT 128
#define NBLK 256
#define POISON64 0x7FC07FC07FC07FC0ULL
#define HSL 262144  // bytes per h step-slice: 16 gt x 1024 rows x 16B

using bf16   = __bf16;
using bf16x8 = __attribute__((ext_vector_type(8))) bf16;
using bf16x4 = __attribute__((ext_vector_type(4))) bf16;
using f32x4  = __attribute__((ext_vector_type(4))) float;
using u64x2  = __attribute__((ext_vector_type(2))) unsigned long long;

template <bool B> struct BoolTag { static constexpr bool value = B; };

__device__ __forceinline__ float fsig(float x) {
  return __builtin_amdgcn_rcpf(1.f + __expf(-x));
}
__device__ __forceinline__ float ftanh(float x) {
  return 2.f * __builtin_amdgcn_rcpf(1.f + __expf(-2.f * x)) - 1.f;
}

// ---- coherent (cross-XCD, IF$-served) helpers ------------------------------
__device__ __forceinline__ void st_u32_coh(unsigned* p, unsigned v) {
  __hip_atomic_store(p, v, __ATOMIC_RELAXED, __HIP_MEMORY_SCOPE_AGENT);
}
__device__ __forceinline__ unsigned ld_u32_coh(const unsigned* p) {
  return __hip_atomic_load((unsigned*)p, __ATOMIC_RELAXED, __HIP_MEMORY_SCOPE_AGENT);
}
__device__ __forceinline__ float ld_f32_coh(const float* p) {
  return __hip_atomic_load((float*)p, __ATOMIC_RELAXED, __HIP_MEMORY_SCOPE_AGENT);
}
__device__ __forceinline__ void st_f32_coh(float* p, float v) {
  __hip_atomic_store(p, v, __ATOMIC_RELAXED, __HIP_MEMORY_SCOPE_AGENT);
}
__device__ __forceinline__ void st_u64_coh(unsigned long long* p, unsigned long long v) {
  __hip_atomic_store(p, v, __ATOMIC_RELAXED, __HIP_MEMORY_SCOPE_AGENT);
}
__device__ __forceinline__ unsigned long long ld_u64_coh(const unsigned long long* p) {
  return __hip_atomic_load((unsigned long long*)p, __ATOMIC_RELAXED, __HIP_MEMORY_SCOPE_AGENT);
}
// nonzero iff some bf16 halfword of v equals POISON (0x7FC0)
__device__ __forceinline__ bool haspoison(unsigned long long v) {
  unsigned long long x = v ^ POISON64;
  return ((x - 0x0001000100010001ULL) & ~x & 0x8000800080008000ULL) != 0ULL;
}

// ---------------------------------------------------------------------------
// prep (single launch):
//  blocks 0..2047   : LDS-tiled x transpose f32[B,T,256] -> bf16[T,row'(b),256]
//                     (fully coalesced both sides) + poison hG/hL slices
//  2048..2559       : WMg with block-local softmax
//  2560             : FM   (block-local softmax)
//  2561             : bias
//  2562..2563       : G0
//  2564             : zero slots
// ---------------------------------------------------------------------------
__global__ void prep(const float* __restrict__ x, const float* __restrict__ mem,
                     const float* __restrict__ b_ih, const float* __restrict__ b_hh,
                     const float* __restrict__ rv0, const float* __restrict__ W_ih,
                     const float* __restrict__ fc_w,
                     bf16* __restrict__ x_bf, char* __restrict__ hG, char* __restrict__ hL,
                     bf16* __restrict__ WMg, float* __restrict__ bias,
                     float* __restrict__ G0, float* __restrict__ FM,
                     unsigned* __restrict__ slots, int fastws) {
  __shared__ char lds[65536];
  const int bid = blockIdx.x, tid = threadIdx.x;
  if (bid < 2048) {
    typedef bf16 (*sTp)[16][256];
    sTp sT = (sTp)lds;  // [4][16][256] = 32 KB
    const int wv = tid >> 6, lane = tid & 63;
    const int bgrp = bid >> 5, tgrp = bid & 31;
    const int B0 = bgrp * 16, t0 = tgrp * 4;
    const int R0 = (bgrp & 15) * 64 + (bgrp >> 4) * 16;  // rowp(b) for b=B0..B0+15 is R0..R0+15
#pragma unroll 4
    for (int it = 0; it < 16; ++it) {
      int r = wv * 16 + it, i = r & 15, tj = r >> 4;
      float4 v = *(const float4*)(x + ((size_t)(B0 + i) * 128 + t0 + tj) * 256 + lane * 4);
      bf16x4 o; o[0] = (bf16)v.x; o[1] = (bf16)v.y; o[2] = (bf16)v.z; o[3] = (bf16)v.w;
      *(bf16x4*)&sT[tj][i][lane * 4] = o;
    }
    __syncthreads();
#pragma unroll 4
    for (int it = 0; it < 16; ++it) {
      int r = wv * 16 + it, i = r & 15, tj = r >> 4;
      *(bf16x4*)(x_bf + ((size_t)(t0 + tj) * BB + R0 + i) * 256 + lane * 4) =
          *(const bf16x4*)&sT[tj][i][lane * 4];
    }
    // poison this block's 16 KB slice(s) of the h arenas
    unsigned long long* pg = (unsigned long long*)(hG + (size_t)bid * 16384 + tid * 64);
#pragma unroll
    for (int q = 0; q < 8; ++q) pg[q] = POISON64;
    if (fastws) {
      unsigned long long* pl = (unsigned long long*)(hL + (size_t)bid * 16384 + tid * 64);
#pragma unroll
      for (int q = 0; q < 8; ++q) pl[q] = POISON64;
    }
  } else if (bid < 2560) {
    float* sSM = (float*)lds;  // [128][128]
    const int g = bid - 2048;
    if (tid < 128) {
      float mx = -1e30f;
      for (int m = 0; m < 128; ++m) mx = fmaxf(mx, mem[m * 128 + tid]);
      float s = 0.f;
      for (int m = 0; m < 128; ++m) s += __expf(mem[m * 128 + tid] - mx);
      float inv = 1.f / s;
      for (int m = 0; m < 128; ++m) sSM[m * 128 + tid] = __expf(mem[m * 128 + tid] - mx) * inv;
    }
    __syncthreads();
    const int r = tid >> 6, n0 = (tid & 63) * 2;
    const float* wr = W_ih + (size_t)g * 768 + 256 + r * 128;
    float a0 = 0.f, a1 = 0.f;
#pragma unroll 4
    for (int m = 0; m < 128; ++m) {
      float2 ms = *(const float2*)(sSM + m * 128 + n0);
      float w = wr[m];
      a0 += w * ms.x;
      a1 += w * ms.y;
    }
    union { bf16 h[2]; unsigned u; } pk;
    pk.h[0] = (bf16)a0; pk.h[1] = (bf16)a1;
    *(unsigned*)(WMg + (size_t)g * 512 + r * 128 + n0) = pk.u;
  } else if (bid == 2560) {
    float* sSM = (float*)lds;
    if (tid < 128) {
      float mx = -1e30f;
      for (int m = 0; m < 128; ++m) mx = fmaxf(mx, mem[m * 128 + tid]);
      float s = 0.f;
      for (int m = 0; m < 128; ++m) s += __expf(mem[m * 128 + tid] - mx);
      float inv = 1.f / s;
      for (int m = 0; m < 128; ++m) sSM[m * 128 + tid] = __expf(mem[m * 128 + tid] - mx) * inv;
    }
    __syncthreads();
    for (int sub = tid; sub < 2 * 512; sub += 256) {
      int o = sub >> 9, rn = sub & 511, rr = rn >> 7, n = rn & 127;
      const float* wr = fc_w + o * 640 + 128 + rr * 128;
      float acc = 0.f;
      for (int m = 0; m < 128; ++m) acc += wr[m] * sSM[m * 128 + n];
      FM[o * 512 + rn] = acc;
    }
  } else if (bid == 2561) {
    for (int e = tid; e < 512; e += 256) bias[e] = b_ih[e] + b_hh[e];
  } else if (bid < 2564) {
    int g = (bid - 2562) * 256 + tid;
    float acc = 0.f;
    for (int k = 0; k < 512; ++k) acc += rv0[k] * W_ih[(size_t)g * 768 + 256 + k];
    G0[g] = acc;
  } else {
    for (int e = tid; e < 4096; e += 256) slots[e] = 0u;
  }
}

// ---------------------------------------------------------------------------
// persistent main: 256 blocks x 256 threads. Decode rt=bid&15, gt=bid>>4 so
// group rt (its 16 blocks) satisfies bid%8==rt%8 -> one XCD under round-robin
// dispatch. Runtime placement check (XCC_ID + one-time barrier) selects:
//  FAST: intra-group Whh h-exchange via XCD-local L2 (plain store -> sc0 load,
//        bounded-retry escape to agent copy); cross-group WM reads stay agent,
//        issued early to overlap with xpart. Producers double-store (hL+hG).
//  SLOW: exact R4 behavior (agent data-as-flag).
// ---------------------------------------------------------------------------
__global__ void __launch_bounds__(256, 1) dnc_main(
    const bf16* __restrict__ x_bf, const bf16* __restrict__ WMg,
    const float* __restrict__ bias, const float* __restrict__ G0,
    const float* __restrict__ FM, char* __restrict__ hG, char* __restrict__ hL,
    float* __restrict__ hsumG, unsigned* __restrict__ slots, unsigned* __restrict__ xcds,
    const float* __restrict__ W_ih, const float* __restrict__ W_hh,
    const float* __restrict__ fc_w, const float* __restrict__ fc_b,
    float* __restrict__ out, int fastws) {
  __shared__ bf16 sWx[32][264];
  __shared__ bf16 sWhh[32][136];
  __shared__ bf16 sWM[32][520];
  __shared__ bf16 sHq[16][520];
  __shared__ __align__(16) unsigned short sStage[4][16][8];
  __shared__ int sFast;

  const int bid = blockIdx.x, tid = threadIdx.x;
  const int rt = bid & 15, gt = bid >> 4;   // XCD-clustered group decode
  const int wave = tid >> 6, lane = tid & 63;
  const int l15 = lane & 15, l4 = lane >> 4;

  unsigned xcc = 0;
  if (fastws) asm volatile("s_getreg_b32 %0, hwreg(HW_REG_XCC_ID)" : "=s"(xcc));

  auto gcol = [&](int pos) { return ((pos >> 3) << 7) + gt * 8 + (pos & 7); };

  for (int e = tid; e < 32 * 256; e += 256) sWx[e >> 8][e & 255] = (bf16)W_ih[(size_t)gcol(e >> 8) * 768 + (e & 255)];
  for (int e = tid; e < 32 * 128; e += 256) sWhh[e >> 7][e & 127] = (bf16)W_hh[gcol(e >> 7) * 128 + (e & 127)];
  for (int e = tid; e < 32 * 512; e += 256) sWM[e >> 9][e & 511] = WMg[(size_t)gcol(e >> 9) * 512 + (e & 511)];
  __syncthreads();

  // placement check: are all 16 blocks of my rt group on my XCD?
  int fast = 0;
  if (fastws) {
    if (tid == 0) st_u32_coh(xcds + bid, xcc);
    asm volatile("s_waitcnt vmcnt(0)" ::: "memory");
    __syncthreads();
    if (tid == 0) st_u32_coh(slots + bid * 16, 1u);
    while (ld_u32_coh(slots + tid * 16) < 1u) {}
    __syncthreads();
    if (tid == 0) sFast = 1;
    __syncthreads();
    if (tid < 16) {
      unsigned px = ld_u32_coh(xcds + (rt + 16 * tid));
      if (px != xcc) sFast = 0;
    }
    __syncthreads();
    fast = sFast;
  }

  const float bv0 = bias[gcol(l15)], bv1 = bias[gcol(16 + l15)];
  const bool lo = (l15 < 8);
  const int j = l15 & 7;
  const int rb = lo ? 0 : 2;
  float cst[2] = {0.f, 0.f}, hsum[2] = {0.f, 0.f};
  int growp[2];
#pragma unroll
  for (int k = 0; k < 2; ++k) growp[k] = rt * 16 + (l4 * 4 + rb + k) + 256 * wave;
  const int myrow = rt * 16 + l15 + 256 * wave;
  const int seg = (lane >> 4) + 4 * wave;

  auto run = [&](auto fc) {
    constexpr bool FAST = decltype(fc)::value;
    f32x4 acc0, acc1;

    auto xpart = [&](int t) {
      acc0 = f32x4{bv0, bv0, bv0, bv0};
      acc1 = f32x4{bv1, bv1, bv1, bv1};
      const bf16* xr = x_bf + ((size_t)t * BB + rt * 64 + wave * 16 + l15) * 256 + l4 * 8;
#pragma unroll
      for (int kk = 0; kk < 8; ++kk) {
        bf16x8 a  = *(const bf16x8*)(xr + kk * 32);
        bf16x8 w0 = *(const bf16x8*)&sWx[l15][kk * 32 + l4 * 8];
        bf16x8 w1 = *(const bf16x8*)&sWx[16 + l15][kk * 32 + l4 * 8];
        acc0 = __builtin_amdgcn_mfma_f32_16x16x32_bf16(a, w0, acc0, 0, 0, 0);
        acc1 = __builtin_amdgcn_mfma_f32_16x16x32_bf16(a, w1, acc1, 0, 0, 0);
      }
    };

    auto pw = [&](bool add_g0, char* hGw, char* hLw) {
      float o0[4], o1[4];
#pragma unroll
      for (int r = 0; r < 4; ++r) {
        o0[r] = __shfl_xor(acc0[r], 8);
        o1[r] = __shfl_xor(acc1[r], 8);
      }
      float g0i = 0.f, g0f = 0.f, g0g = 0.f, g0o = 0.f;
      if (add_g0) {
        int cb = gt * 8 + j;
        g0i = G0[cb]; g0f = G0[128 + cb]; g0g = G0[256 + cb]; g0o = G0[384 + cb];
      }
#pragma unroll
      for (int k = 0; k < 2; ++k) {
        int r = rb + k;
        float gi = (lo ? acc0[r] : o0[r]) + g0i;
        float gf = (lo ? o0[r] : acc0[r]) + g0f;
        float gg = (lo ? acc1[r] : o1[r]) + g0g;
        float go = (lo ? o1[r] : acc1[r]) + g0o;
        cst[k] = fsig(gf) * cst[k] + fsig(gi) * ftanh(gg);
        float h = fsig(go) * ftanh(cst[k]);
        hsum[k] += h;
        union { bf16 b; unsigned short u; } cv; cv.b = (bf16)h;
        sStage[wave][l4 * 4 + rb + k][j] = cv.u;
      }
      asm volatile("" ::: "memory");
      if (lane < 32) {
        unsigned long long v = *(const unsigned long long*)&sStage[wave][lane >> 1][(lane & 1) * 4];
        int row = rt * 16 + 256 * wave + (lane >> 1);
        size_t off = ((size_t)(gt * 1024 + row)) * 16 + (lane & 1) * 8;
        st_u64_coh((unsigned long long*)(hGw + off), v);
        if constexpr (FAST) *(unsigned long long*)(hLw + off) = v;
      }
    };

    xpart(0);
    pw(true, hG, hL);
    for (int t = 1; t < TT; ++t) {
      const char* hGr = hG + (size_t)(t - 1) * HSL;
      const char* hLr = hL + (size_t)(t - 1) * HSL;
      const unsigned long long* hG64 = (const unsigned long long*)hGr;
      // ---- early issue: ia (Whh rows, intra-group) -------------------------
      u64x2 vq[4];
      unsigned long long va[8];
      if constexpr (FAST) {
#pragma unroll
        for (int kk = 0; kk < 4; ++kk)
          asm volatile("global_load_dwordx4 %0, %1, off sc0"
                       : "=v"(vq[kk])
                       : "v"(hLr + ((size_t)((kk * 4 + l4) * 1024 + myrow)) * 16));
      } else {
#pragma unroll
        for (int kk = 0; kk < 4; ++kk) {
          va[2 * kk]     = ld_u64_coh(hG64 + ((kk * 4 + l4) * 1024 + myrow) * 2);
          va[2 * kk + 1] = ld_u64_coh(hG64 + ((kk * 4 + l4) * 1024 + myrow) * 2 + 1);
        }
      }
      // ---- early issue: ist (WM rows, cross-group -> agent) ----------------
      unsigned long long vs[8];
      int ist[4];
#pragma unroll
      for (int p = 0; p < 4; ++p) ist[p] = (seg * 1024 + rt * 64 + (lane & 15) + 16 * p) * 2;
#pragma unroll
      for (int p = 0; p < 4; ++p) {
        vs[2 * p]     = ld_u64_coh(hG64 + ist[p]);
        vs[2 * p + 1] = ld_u64_coh(hG64 + ist[p] + 1);
      }
      xpart(t);  // latency of all the above overlaps this
      // ---- ia poll + Whh MFMAs --------------------------------------------
      if constexpr (FAST) {
        int tries = 0; bool esc = false;
        for (;;) {
          asm volatile("s_waitcnt vmcnt(0)" ::: "memory");
          __builtin_amdgcn_sched_barrier(0);
          unsigned st = 0;
#pragma unroll
          for (int kk = 0; kk < 4; ++kk)
            st |= (haspoison(vq[kk][0]) || haspoison(vq[kk][1])) ? (1u << kk) : 0u;
          if (!st) break;
          __builtin_amdgcn_s_sleep(1);
          if (++tries >= 256) esc = true;  // safety net: agent copy always valid
          if (esc) {
#pragma unroll
            for (int kk = 0; kk < 4; ++kk)
              if (st & (1u << kk)) {
                vq[kk][0] = ld_u64_coh(hG64 + ((kk * 4 + l4) * 1024 + myrow) * 2);
                vq[kk][1] = ld_u64_coh(hG64 + ((kk * 4 + l4) * 1024 + myrow) * 2 + 1);
              }
          } else {
#pragma unroll
            for (int kk = 0; kk < 4; ++kk)
              asm volatile("global_load_dwordx4 %0, %1, off sc0"
                           : "=v"(vq[kk])
                           : "v"(hLr + ((size_t)((kk * 4 + l4) * 1024 + myrow)) * 16));
          }
        }
#pragma unroll
        for (int kk = 0; kk < 4; ++kk) {
          union { u64x2 q; bf16x8 b; } c; c.q = vq[kk];
          bf16x8 w0 = *(const bf16x8*)&sWhh[l15][kk * 32 + l4 * 8];
          bf16x8 w1 = *(const bf16x8*)&sWhh[16 + l15][kk * 32 + l4 * 8];
          acc0 = __builtin_amdgcn_mfma_f32_16x16x32_bf16(c.b, w0, acc0, 0, 0, 0);
          acc1 = __builtin_amdgcn_mfma_f32_16x16x32_bf16(c.b, w1, acc1, 0, 0, 0);
        }
      } else {
        for (;;) {
          unsigned st = 0;
#pragma unroll
          for (int i = 0; i < 8; ++i) st |= haspoison(va[i]) ? (1u << i) : 0u;
          if (!st) break;
          __builtin_amdgcn_s_sleep(1);
#pragma unroll
          for (int i = 0; i < 8; ++i)
            if (st & (1u << i)) va[i] = ld_u64_coh(hG64 + (((i >> 1) * 4 + l4) * 1024 + myrow) * 2 + (i & 1));
        }
#pragma unroll
        for (int kk = 0; kk < 4; ++kk) {
          union { unsigned long long u[2]; bf16x8 b; } c;
          c.u[0] = va[2 * kk]; c.u[1] = va[2 * kk + 1];
          bf16x8 w0 = *(const bf16x8*)&sWhh[l15][kk * 32 + l4 * 8];
          bf16x8 w1 = *(const bf16x8*)&sWhh[16 + l15][kk * 32 + l4 * 8];
          acc0 = __builtin_amdgcn_mfma_f32_16x16x32_bf16(c.b, w0, acc0, 0, 0, 0);
          acc1 = __builtin_amdgcn_mfma_f32_16x16x32_bf16(c.b, w1, acc1, 0, 0, 0);
        }
      }
      __syncthreads();  // all waves done reading prev-step sHq
      // ---- ist poll (agent, both paths) -----------------------------------
      for (;;) {
        unsigned st = 0;
#pragma unroll
        for (int i = 0; i < 8; ++i) st |= haspoison(vs[i]) ? (1u << i) : 0u;
        if (!st) break;
        __builtin_amdgcn_s_sleep(1);
#pragma unroll
        for (int i = 0; i < 8; ++i)
          if (st & (1u << i)) vs[i] = ld_u64_coh(hG64 + ist[i >> 1] + (i & 1));
      }
#pragma unroll
      for (int p = 0; p < 4; ++p) {
        int row64 = (lane & 15) + 16 * p;
        union { unsigned long long u[2]; bf16x8 b; } c;
        c.u[0] = vs[2 * p]; c.u[1] = vs[2 * p + 1];
        *(bf16x8*)&sHq[row64 >> 2][(row64 & 3) * 128 + seg * 8] = c.b;
      }
      __syncthreads();  // sHq ready
#pragma unroll
      for (int kk = 0; kk < 16; ++kk) {
        bf16x8 a  = *(const bf16x8*)&sHq[l15][kk * 32 + l4 * 8];
        bf16x8 w0 = *(const bf16x8*)&sWM[l15][kk * 32 + l4 * 8];
        bf16x8 w1 = *(const bf16x8*)&sWM[16 + l15][kk * 32 + l4 * 8];
        acc0 = __builtin_amdgcn_mfma_f32_16x16x32_bf16(a, w0, acc0, 0, 0, 0);
        acc1 = __builtin_amdgcn_mfma_f32_16x16x32_bf16(a, w1, acc1, 0, 0, 0);
      }
      pw(false, hG + (size_t)t * HSL, hL + (size_t)t * HSL);
    }
  };

  if (fast) run(BoolTag<true>{});
  else      run(BoolTag<false>{});

  // epilogue: hsum -> global, one-shot slot barrier, fused mean+projection
  const unsigned EPI = fastws ? 2u : 1u;
#pragma unroll
  for (int k = 0; k < 2; ++k)
    st_f32_coh(hsumG + (size_t)growp[k] * 128 + gt * 8 + j, hsum[k]);
  asm volatile("s_waitcnt vmcnt(0)" ::: "memory");
  __syncthreads();
  if (tid == 0) st_u32_coh(slots + bid * 16, EPI);
  while (ld_u32_coh(slots + tid * 16) < EPI) {}
  __syncthreads();
  {
    int row = bid * 4 + wave;
    const float* hsr = hsumG + (size_t)row * 128;
    const float* hqr = hsumG + (size_t)(row & 255) * 512;
    float s0 = 0.f, s1 = 0.f;
    for (int k = lane; k < 128; k += 64) { float v = ld_f32_coh(hsr + k); s0 += v * fc_w[k]; s1 += v * fc_w[640 + k]; }
    for (int k = lane; k < 512; k += 64) { float v = ld_f32_coh(hqr + k); s0 += v * FM[k]; s1 += v * FM[512 + k]; }
    for (int off = 32; off > 0; off >>= 1) { s0 += __shfl_down(s0, off); s1 += __shfl_down(s1, off); }
    if (lane == 0) {
      out[row * 2 + 0] = s0 * (1.f / 128.f) + fc_b[0];
      out[row * 2 + 1] = s1 * (1.f / 128.f) + fc_b[1];
    }
  }
}

// ---------------------------------------------------------------------------
extern "C" void kernel_launch(void* const* d_in, const int* in_sizes, int n_in,
                              void* d_out, int out_size, void* d_ws, size_t ws_size,
                              hipStream_t stream) {
  const float* x      = (const float*)d_in[0];
  const float* memory = (const float*)d_in[1];
  const float* rv0    = (const float*)d_in[2];
  const float* W_ih   = (const float*)d_in[3];
  const float* W_hh   = (const float*)d_in[4];
  const float* b_ih   = (const float*)d_in[5];
  const float* b_hh   = (const float*)d_in[6];
  const float* fc_w   = (const float*)d_in[7];
  const float* fc_b   = (const float*)d_in[8];
  float* out = (float*)d_out;
  char* ws = (char*)d_ws;

  bf16*     x_bf  = (bf16*)ws;                      //  67,108,864
  bf16*     WMg   = (bf16*)(ws + 67108864);         //     524,288
  float*    bias  = (float*)(ws + 67633152);        //       2,048
  float*    G0    = (float*)(ws + 67635200);        //       2,048
  float*    FM    = (float*)(ws + 67637248);        //       4,096
  unsigned* slots = (unsigned*)(ws + 67641344);     //      16,384
  unsigned* xcds  = (unsigned*)(ws + 67657728);     //       4,096
  float*    hsumG = (float*)(ws + 67661824);        //     524,288
  char*     hG    = ws + 68186112;                  //  33,554,432
  char*     hL    = ws + 101740544;                 //  33,554,432 (end 135,294,976)

  int fastws = (ws_size >= 135294976u) ? 1 : 0;
  if (!fastws) hL = hG;  // never dereferenced as distinct in slow mode

  prep<<<2565, 256, 0, stream>>>(x, memory, b_ih, b_hh, rv0, W_ih, fc_w,
                                 x_bf, hG, hL, WMg, bias, G0, FM, slots, fastws);
  dnc_main<<<NBLK, 256, 0, stream>>>(x_bf, WMg, bias, G0, FM, hG, hL, hsumG, slots, xcds,
                                     W_ih, W_hh, fc_w, fc_b, out, fastws);
}

// Round 6
// 922.825 us; speedup vs baseline: 13.8345x; 13.8345x over previous
//
#include <hip/hip_runtime.h>

#define BB 1024
#define TT 128
#define NBLK 256
#define POISON64 0x7FC07FC07FC07FC0ULL
#define HSL 262144  // bytes per h step-slice: 16 gt x 1024 rows x 16B

using bf16   = __bf16;
using bf16x8 = __attribute__((ext_vector_type(8))) bf16;
using bf16x4 = __attribute__((ext_vector_type(4))) bf16;
using f32x4  = __attribute__((ext_vector_type(4))) float;

__device__ __forceinline__ float fsig(float x) {
  return __builtin_amdgcn_rcpf(1.f + __expf(-x));
}
__device__ __forceinline__ float ftanh(float x) {
  return 2.f * __builtin_amdgcn_rcpf(1.f + __expf(-2.f * x)) - 1.f;
}

// ---- coherent (cross-XCD, IF$-served) helpers ------------------------------
__device__ __forceinline__ void st_u32_coh(unsigned* p, unsigned v) {
  __hip_atomic_store(p, v, __ATOMIC_RELAXED, __HIP_MEMORY_SCOPE_AGENT);
}
__device__ __forceinline__ unsigned ld_u32_coh(const unsigned* p) {
  return __hip_atomic_load((unsigned*)p, __ATOMIC_RELAXED, __HIP_MEMORY_SCOPE_AGENT);
}
__device__ __forceinline__ float ld_f32_coh(const float* p) {
  return __hip_atomic_load((float*)p, __ATOMIC_RELAXED, __HIP_MEMORY_SCOPE_AGENT);
}
__device__ __forceinline__ void st_f32_coh(float* p, float v) {
  __hip_atomic_store(p, v, __ATOMIC_RELAXED, __HIP_MEMORY_SCOPE_AGENT);
}
__device__ __forceinline__ void st_u64_coh(unsigned long long* p, unsigned long long v) {
  __hip_atomic_store(p, v, __ATOMIC_RELAXED, __HIP_MEMORY_SCOPE_AGENT);
}
__device__ __forceinline__ unsigned long long ld_u64_coh(const unsigned long long* p) {
  return __hip_atomic_load((unsigned long long*)p, __ATOMIC_RELAXED, __HIP_MEMORY_SCOPE_AGENT);
}
// nonzero iff some bf16 halfword of v equals POISON (0x7FC0)
__device__ __forceinline__ bool haspoison(unsigned long long v) {
  unsigned long long x = v ^ POISON64;
  return ((x - 0x0001000100010001ULL) & ~x & 0x8000800080008000ULL) != 0ULL;
}

// ---------------------------------------------------------------------------
// prep (single launch):
//  blocks 0..2047 : LDS-tiled x transpose f32[B,T,256] -> bf16[T,row'(b),256]
//                   (coalesced both sides) + poison hG slices
//  2048..2559     : WMg with block-local softmax
//  2560           : FM   2561: bias   2562..2563: G0   2564: zero slots
// ---------------------------------------------------------------------------
__global__ void prep(const float* __restrict__ x, const float* __restrict__ mem,
                     const float* __restrict__ b_ih, const float* __restrict__ b_hh,
                     const float* __restrict__ rv0, const float* __restrict__ W_ih,
                     const float* __restrict__ fc_w,
                     bf16* __restrict__ x_bf, char* __restrict__ hG,
                     bf16* __restrict__ WMg, float* __restrict__ bias,
                     float* __restrict__ G0, float* __restrict__ FM,
                     unsigned* __restrict__ slots) {
  __shared__ char lds[65536];
  const int bid = blockIdx.x, tid = threadIdx.x;
  if (bid < 2048) {
    typedef bf16 (*sTp)[16][256];
    sTp sT = (sTp)lds;  // [4][16][256] = 32 KB
    const int wv = tid >> 6, lane = tid & 63;
    const int bgrp = bid >> 5, tgrp = bid & 31;
    const int B0 = bgrp * 16, t0 = tgrp * 4;
    const int R0 = (bgrp & 15) * 64 + (bgrp >> 4) * 16;
#pragma unroll 4
    for (int it = 0; it < 16; ++it) {
      int r = wv * 16 + it, i = r & 15, tj = r >> 4;
      float4 v = *(const float4*)(x + ((size_t)(B0 + i) * 128 + t0 + tj) * 256 + lane * 4);
      bf16x4 o; o[0] = (bf16)v.x; o[1] = (bf16)v.y; o[2] = (bf16)v.z; o[3] = (bf16)v.w;
      *(bf16x4*)&sT[tj][i][lane * 4] = o;
    }
    __syncthreads();
#pragma unroll 4
    for (int it = 0; it < 16; ++it) {
      int r = wv * 16 + it, i = r & 15, tj = r >> 4;
      *(bf16x4*)(x_bf + ((size_t)(t0 + tj) * BB + R0 + i) * 256 + lane * 4) =
          *(const bf16x4*)&sT[tj][i][lane * 4];
    }
    // poison this block's 16 KB slice of the h arena
    unsigned long long* pg = (unsigned long long*)(hG + (size_t)bid * 16384 + tid * 64);
#pragma unroll
    for (int q = 0; q < 8; ++q) pg[q] = POISON64;
  } else if (bid < 2560) {
    float* sSM = (float*)lds;  // [128][128]
    const int g = bid - 2048;
    if (tid < 128) {
      float mx = -1e30f;
      for (int m = 0; m < 128; ++m) mx = fmaxf(mx, mem[m * 128 + tid]);
      float s = 0.f;
      for (int m = 0; m < 128; ++m) s += __expf(mem[m * 128 + tid] - mx);
      float inv = 1.f / s;
      for (int m = 0; m < 128; ++m) sSM[m * 128 + tid] = __expf(mem[m * 128 + tid] - mx) * inv;
    }
    __syncthreads();
    const int r = tid >> 6, n0 = (tid & 63) * 2;
    const float* wr = W_ih + (size_t)g * 768 + 256 + r * 128;
    float a0 = 0.f, a1 = 0.f;
#pragma unroll 4
    for (int m = 0; m < 128; ++m) {
      float2 ms = *(const float2*)(sSM + m * 128 + n0);
      float w = wr[m];
      a0 += w * ms.x;
      a1 += w * ms.y;
    }
    union { bf16 h[2]; unsigned u; } pk;
    pk.h[0] = (bf16)a0; pk.h[1] = (bf16)a1;
    *(unsigned*)(WMg + (size_t)g * 512 + r * 128 + n0) = pk.u;
  } else if (bid == 2560) {
    float* sSM = (float*)lds;
    if (tid < 128) {
      float mx = -1e30f;
      for (int m = 0; m < 128; ++m) mx = fmaxf(mx, mem[m * 128 + tid]);
      float s = 0.f;
      for (int m = 0; m < 128; ++m) s += __expf(mem[m * 128 + tid] - mx);
      float inv = 1.f / s;
      for (int m = 0; m < 128; ++m) sSM[m * 128 + tid] = __expf(mem[m * 128 + tid] - mx) * inv;
    }
    __syncthreads();
    for (int sub = tid; sub < 2 * 512; sub += 256) {
      int o = sub >> 9, rn = sub & 511, rr = rn >> 7, n = rn & 127;
      const float* wr = fc_w + o * 640 + 128 + rr * 128;
      float acc = 0.f;
      for (int m = 0; m < 128; ++m) acc += wr[m] * sSM[m * 128 + n];
      FM[o * 512 + rn] = acc;
    }
  } else if (bid == 2561) {
    for (int e = tid; e < 512; e += 256) bias[e] = b_ih[e] + b_hh[e];
  } else if (bid < 2564) {
    int g = (bid - 2562) * 256 + tid;
    float acc = 0.f;
    for (int k = 0; k < 512; ++k) acc += rv0[k] * W_ih[(size_t)g * 768 + 256 + k];
    G0[g] = acc;
  } else {
    for (int e = tid; e < 4096; e += 256) slots[e] = 0u;
  }
}

// ---------------------------------------------------------------------------
// persistent main: 256 blocks x 256 threads. R4's agent-scope data-as-flag
// exchange (the only reliably-visible path — R5 proved XCD-local L2 exchange
// is not timely). Changes vs R4:
//  - decode rt=bid&15 (same-rt blocks colocate per XCD -> x reads L2-hit)
//  - ia/ist loads issued BEFORE xpart (latency overlaps the x GEMM)
//  - accumulators split per K-segment (dependent-MFMA chains 56 -> <=8)
// ---------------------------------------------------------------------------
__global__ void __launch_bounds__(256, 1) dnc_main(
    const bf16* __restrict__ x_bf, const bf16* __restrict__ WMg,
    const float* __restrict__ bias, const float* __restrict__ G0,
    const float* __restrict__ FM, char* __restrict__ hG,
    float* __restrict__ hsumG, unsigned* __restrict__ slots,
    const float* __restrict__ W_ih, const float* __restrict__ W_hh,
    const float* __restrict__ fc_w, const float* __restrict__ fc_b,
    float* __restrict__ out) {
  __shared__ bf16 sWx[32][264];
  __shared__ bf16 sWhh[32][136];
  __shared__ bf16 sWM[32][520];
  __shared__ bf16 sHq[16][520];
  __shared__ __align__(16) unsigned short sStage[4][16][8];

  const int bid = blockIdx.x, tid = threadIdx.x;
  const int rt = bid & 15, gt = bid >> 4;   // XCD-clustered group decode
  const int wave = tid >> 6, lane = tid & 63;
  const int l15 = lane & 15, l4 = lane >> 4;

  auto gcol = [&](int pos) { return ((pos >> 3) << 7) + gt * 8 + (pos & 7); };

  for (int e = tid; e < 32 * 256; e += 256) sWx[e >> 8][e & 255] = (bf16)W_ih[(size_t)gcol(e >> 8) * 768 + (e & 255)];
  for (int e = tid; e < 32 * 128; e += 256) sWhh[e >> 7][e & 127] = (bf16)W_hh[gcol(e >> 7) * 128 + (e & 127)];
  for (int e = tid; e < 32 * 512; e += 256) sWM[e >> 9][e & 511] = WMg[(size_t)gcol(e >> 9) * 512 + (e & 511)];
  __syncthreads();

  const float bv0 = bias[gcol(l15)], bv1 = bias[gcol(16 + l15)];
  const bool lo = (l15 < 8);
  const int j = l15 & 7;
  const int rb = lo ? 0 : 2;
  float cst[2] = {0.f, 0.f}, hsum[2] = {0.f, 0.f};
  int growp[2];
#pragma unroll
  for (int k = 0; k < 2; ++k) growp[k] = rt * 16 + (l4 * 4 + rb + k) + 256 * wave;
  const int myrow = rt * 16 + l15 + 256 * wave;
  const int seg = (lane >> 4) + 4 * wave;

  // split accumulators: X (x-part), H (Whh), Wa/Wb (WM halves)
  f32x4 aX0, aX1;
  f32x4 aH0 = {0,0,0,0}, aH1 = {0,0,0,0};
  f32x4 aWa0 = {0,0,0,0}, aWa1 = {0,0,0,0}, aWb0 = {0,0,0,0}, aWb1 = {0,0,0,0};

  auto xpart = [&](int t) {
    aX0 = f32x4{bv0, bv0, bv0, bv0};
    aX1 = f32x4{bv1, bv1, bv1, bv1};
    const bf16* xr = x_bf + ((size_t)t * BB + rt * 64 + wave * 16 + l15) * 256 + l4 * 8;
#pragma unroll
    for (int kk = 0; kk < 8; ++kk) {
      bf16x8 a  = *(const bf16x8*)(xr + kk * 32);
      bf16x8 w0 = *(const bf16x8*)&sWx[l15][kk * 32 + l4 * 8];
      bf16x8 w1 = *(const bf16x8*)&sWx[16 + l15][kk * 32 + l4 * 8];
      aX0 = __builtin_amdgcn_mfma_f32_16x16x32_bf16(a, w0, aX0, 0, 0, 0);
      aX1 = __builtin_amdgcn_mfma_f32_16x16x32_bf16(a, w1, aX1, 0, 0, 0);
    }
  };

  auto pw = [&](bool add_g0, char* hGw) {
    // combine split accumulators
    f32x4 c0, c1;
#pragma unroll
    for (int r = 0; r < 4; ++r) {
      c0[r] = aX0[r] + aH0[r] + aWa0[r] + aWb0[r];
      c1[r] = aX1[r] + aH1[r] + aWa1[r] + aWb1[r];
    }
    float o0[4], o1[4];
#pragma unroll
    for (int r = 0; r < 4; ++r) {
      o0[r] = __shfl_xor(c0[r], 8);
      o1[r] = __shfl_xor(c1[r], 8);
    }
    float g0i = 0.f, g0f = 0.f, g0g = 0.f, g0o = 0.f;
    if (add_g0) {
      int cb = gt * 8 + j;
      g0i = G0[cb]; g0f = G0[128 + cb]; g0g = G0[256 + cb]; g0o = G0[384 + cb];
    }
#pragma unroll
    for (int k = 0; k < 2; ++k) {
      int r = rb + k;
      float gi = (lo ? c0[r] : o0[r]) + g0i;
      float gf = (lo ? o0[r] : c0[r]) + g0f;
      float gg = (lo ? c1[r] : o1[r]) + g0g;
      float go = (lo ? o1[r] : c1[r]) + g0o;
      cst[k] = fsig(gf) * cst[k] + fsig(gi) * ftanh(gg);
      float h = fsig(go) * ftanh(cst[k]);
      hsum[k] += h;
      union { bf16 b; unsigned short u; } cv; cv.b = (bf16)h;
      sStage[wave][l4 * 4 + rb + k][j] = cv.u;
    }
    asm volatile("" ::: "memory");
    if (lane < 32) {
      unsigned long long v = *(const unsigned long long*)&sStage[wave][lane >> 1][(lane & 1) * 4];
      int row = rt * 16 + 256 * wave + (lane >> 1);
      size_t off = ((size_t)(gt * 1024 + row)) * 16 + (lane & 1) * 8;
      st_u64_coh((unsigned long long*)(hGw + off), v);
    }
  };

  // ---- timeline: fully elastic; producer never waits ----------------------
  xpart(0);
  pw(true, hG);
  for (int t = 1; t < TT; ++t) {
    const unsigned long long* hG64 = (const unsigned long long*)(hG + (size_t)(t - 1) * HSL);
    // early issue: ia (Whh rows) + ist (WM staging rows) — overlap with xpart
    unsigned long long va[8], vs[8];
    int ist[4];
#pragma unroll
    for (int kk = 0; kk < 4; ++kk) {
      va[2 * kk]     = ld_u64_coh(hG64 + ((kk * 4 + l4) * 1024 + myrow) * 2);
      va[2 * kk + 1] = ld_u64_coh(hG64 + ((kk * 4 + l4) * 1024 + myrow) * 2 + 1);
    }
#pragma unroll
    for (int p = 0; p < 4; ++p) ist[p] = (seg * 1024 + rt * 64 + (lane & 15) + 16 * p) * 2;
#pragma unroll
    for (int p = 0; p < 4; ++p) {
      vs[2 * p]     = ld_u64_coh(hG64 + ist[p]);
      vs[2 * p + 1] = ld_u64_coh(hG64 + ist[p] + 1);
    }
    xpart(t);  // x GEMM overlaps the load latency above
    // ---- ia poll + Whh MFMAs (independent acc; chain <= 4) ----------------
    for (;;) {
      unsigned st = 0;
#pragma unroll
      for (int i = 0; i < 8; ++i) st |= haspoison(va[i]) ? (1u << i) : 0u;
      if (!st) break;
      __builtin_amdgcn_s_sleep(1);
#pragma unroll
      for (int i = 0; i < 8; ++i)
        if (st & (1u << i)) va[i] = ld_u64_coh(hG64 + (((i >> 1) * 4 + l4) * 1024 + myrow) * 2 + (i & 1));
    }
    aH0 = f32x4{0,0,0,0}; aH1 = f32x4{0,0,0,0};
#pragma unroll
    for (int kk = 0; kk < 4; ++kk) {
      union { unsigned long long u[2]; bf16x8 b; } c;
      c.u[0] = va[2 * kk]; c.u[1] = va[2 * kk + 1];
      bf16x8 w0 = *(const bf16x8*)&sWhh[l15][kk * 32 + l4 * 8];
      bf16x8 w1 = *(const bf16x8*)&sWhh[16 + l15][kk * 32 + l4 * 8];
      aH0 = __builtin_amdgcn_mfma_f32_16x16x32_bf16(c.b, w0, aH0, 0, 0, 0);
      aH1 = __builtin_amdgcn_mfma_f32_16x16x32_bf16(c.b, w1, aH1, 0, 0, 0);
    }
    __syncthreads();  // all waves done reading prev-step sHq
    // ---- ist poll, build sHq ----------------------------------------------
    for (;;) {
      unsigned st = 0;
#pragma unroll
      for (int i = 0; i < 8; ++i) st |= haspoison(vs[i]) ? (1u << i) : 0u;
      if (!st) break;
      __builtin_amdgcn_s_sleep(1);
#pragma unroll
      for (int i = 0; i < 8; ++i)
        if (st & (1u << i)) vs[i] = ld_u64_coh(hG64 + ist[i >> 1] + (i & 1));
    }
#pragma unroll
    for (int p = 0; p < 4; ++p) {
      int row64 = (lane & 15) + 16 * p;
      union { unsigned long long u[2]; bf16x8 b; } c;
      c.u[0] = vs[2 * p]; c.u[1] = vs[2 * p + 1];
      *(bf16x8*)&sHq[row64 >> 2][(row64 & 3) * 128 + seg * 8] = c.b;
    }
    __syncthreads();  // sHq ready
    // ---- WM MFMAs split into two independent chains of 8 ------------------
    aWa0 = f32x4{0,0,0,0}; aWa1 = f32x4{0,0,0,0};
    aWb0 = f32x4{0,0,0,0}; aWb1 = f32x4{0,0,0,0};
#pragma unroll
    for (int kk = 0; kk < 8; ++kk) {
      bf16x8 a  = *(const bf16x8*)&sHq[l15][kk * 32 + l4 * 8];
      bf16x8 w0 = *(const bf16x8*)&sWM[l15][kk * 32 + l4 * 8];
      bf16x8 w1 = *(const bf16x8*)&sWM[16 + l15][kk * 32 + l4 * 8];
      aWa0 = __builtin_amdgcn_mfma_f32_16x16x32_bf16(a, w0, aWa0, 0, 0, 0);
      aWa1 = __builtin_amdgcn_mfma_f32_16x16x32_bf16(a, w1, aWa1, 0, 0, 0);
    }
#pragma unroll
    for (int kk = 8; kk < 16; ++kk) {
      bf16x8 a  = *(const bf16x8*)&sHq[l15][kk * 32 + l4 * 8];
      bf16x8 w0 = *(const bf16x8*)&sWM[l15][kk * 32 + l4 * 8];
      bf16x8 w1 = *(const bf16x8*)&sWM[16 + l15][kk * 32 + l4 * 8];
      aWb0 = __builtin_amdgcn_mfma_f32_16x16x32_bf16(a, w0, aWb0, 0, 0, 0);
      aWb1 = __builtin_amdgcn_mfma_f32_16x16x32_bf16(a, w1, aWb1, 0, 0, 0);
    }
    pw(false, hG + (size_t)t * HSL);
  }

  // epilogue: hsum -> global, one-shot slot barrier, fused mean+projection
#pragma unroll
  for (int k = 0; k < 2; ++k)
    st_f32_coh(hsumG + (size_t)growp[k] * 128 + gt * 8 + j, hsum[k]);
  asm volatile("s_waitcnt vmcnt(0)" ::: "memory");
  __syncthreads();
  if (tid == 0) st_u32_coh(slots + bid * 16, 1u);
  while (ld_u32_coh(slots + tid * 16) < 1u) {}
  __syncthreads();
  {
    int row = bid * 4 + wave;
    const float* hsr = hsumG + (size_t)row * 128;
    const float* hqr = hsumG + (size_t)(row & 255) * 512;
    float s0 = 0.f, s1 = 0.f;
    for (int k = lane; k < 128; k += 64) { float v = ld_f32_coh(hsr + k); s0 += v * fc_w[k]; s1 += v * fc_w[640 + k]; }
    for (int k = lane; k < 512; k += 64) { float v = ld_f32_coh(hqr + k); s0 += v * FM[k]; s1 += v * FM[512 + k]; }
    for (int off = 32; off > 0; off >>= 1) { s0 += __shfl_down(s0, off); s1 += __shfl_down(s1, off); }
    if (lane == 0) {
      out[row * 2 + 0] = s0 * (1.f / 128.f) + fc_b[0];
      out[row * 2 + 1] = s1 * (1.f / 128.f) + fc_b[1];
    }
  }
}

// ---------------------------------------------------------------------------
extern "C" void kernel_launch(void* const* d_in, const int* in_sizes, int n_in,
                              void* d_out, int out_size, void* d_ws, size_t ws_size,
                              hipStream_t stream) {
  const float* x      = (const float*)d_in[0];
  const float* memory = (const float*)d_in[1];
  const float* rv0    = (const float*)d_in[2];
  const float* W_ih   = (const float*)d_in[3];
  const float* W_hh   = (const float*)d_in[4];
  const float* b_ih   = (const float*)d_in[5];
  const float* b_hh   = (const float*)d_in[6];
  const float* fc_w   = (const float*)d_in[7];
  const float* fc_b   = (const float*)d_in[8];
  float* out = (float*)d_out;
  char* ws = (char*)d_ws;

  bf16*     x_bf  = (bf16*)ws;                      //  67,108,864
  bf16*     WMg   = (bf16*)(ws + 67108864);         //     524,288
  float*    bias  = (float*)(ws + 67633152);        //       2,048
  float*    G0    = (float*)(ws + 67635200);        //       2,048
  float*    FM    = (float*)(ws + 67637248);        //       4,096
  unsigned* slots = (unsigned*)(ws + 67641344);     //      16,384
  float*    hsumG = (float*)(ws + 67657728);        //     524,288
  char*     hG    = ws + 68182016;                  //  33,554,432 (end 101,736,448)

  prep<<<2565, 256, 0, stream>>>(x, memory, b_ih, b_hh, rv0, W_ih, fc_w,
                                 x_bf, hG, WMg, bias, G0, FM, slots);
  dnc_main<<<NBLK, 256, 0, stream>>>(x_bf, WMg, bias, G0, FM, hG, hsumG, slots,
                                     W_ih, W_hh, fc_w, fc_b, out);
}